// Round 6
// baseline (88.247 us; speedup 1.0000x reference)
//
#include <hip/hip_runtime.h>

// Problem constants (fixed by the reference)
constexpr int B = 8, T = 128, S = 256, H = 512;

typedef __attribute__((ext_vector_type(4))) float f32x4;
typedef __attribute__((ext_vector_type(8))) short short8;
typedef __attribute__((ext_vector_type(4))) short short4v;

#define DEVINL __device__ __forceinline__

DEVINL float bf2f(short s) {
  union { unsigned u; float f; } x;
  x.u = ((unsigned)(unsigned short)s) << 16;
  return x.f;
}
// fp32 -> bf16 round-to-nearest-even (finite inputs)
DEVINL short f2bf(float f) {
  unsigned u = __float_as_uint(f);
  return (short)((u + 0x7fffu + ((u >> 16) & 1u)) >> 16);
}
DEVINL float fast_tanh(float x) {
  float e = __builtin_amdgcn_exp2f(x * 2.8853900817779268f);
  return 1.0f - 2.0f * __builtin_amdgcn_rcpf(e + 1.0f);
}

constexpr float C2 = 2.8853900817779268f;   // 2*log2(e) — folded into W_s, W_h
constexpr float L2E = 1.4426950408889634f;  // log2(e)

// ---- workspace layout (units: shorts) — 4,980,736 shorts = 9.5 MiB ----
constexpr size_t OFF_WSB = 0;                               // C2*W_s bf16  (H*H)
constexpr size_t OFF_WHB = OFF_WSB + (size_t)H * H;         // C2*W_h bf16  (H*H)
constexpr size_t OFF_WOB = OFF_WHB + (size_t)H * H;         // W_out bf16   (H*2H)
constexpr size_t OFF_EH  = OFF_WOB + (size_t)H * 2 * H;     // exp2(hs')^T bf16 (B*H*S)
constexpr size_t OFF_ET  = OFF_EH + (size_t)B * H * S;      // enc^T bf16   (B*H*S)
constexpr size_t OFF_ATT = OFF_ET + (size_t)B * H * S;      // attn bf16    (B*T*S)
constexpr size_t OFF_CTX = OFF_ATT + (size_t)B * T * S;     // ctx bf16     (B*T*H)
constexpr size_t OFF_EQ  = OFF_CTX + (size_t)B * T * H;     // exp2(qs') f32 (B*T*H floats)

// ---- prep: blocks [0,256): enc f32 -> e_t[b][h][s] bf16 (LDS-tiled transpose);
//            blocks [256,1280): weights fp32 -> bf16 (W_s, W_h pre-scaled by C2) ----
__global__ __launch_bounds__(256) void prep_kernel(
    const float* __restrict__ ws, const float* __restrict__ wh,
    const float* __restrict__ wo, const float* __restrict__ enc,
    short* __restrict__ base) {
  __shared__ float tile[64][65];
  const int tid = threadIdx.x;
  if (blockIdx.x < 256) {
    short* e_t = base + OFF_ET;
    const int bid = blockIdx.x;
    const int b = bid >> 5;
    const int s0 = ((bid >> 3) & 3) * 64;
    const int h0 = (bid & 7) * 64;
#pragma unroll
    for (int p = 0; p < 4; ++p) {
      const int idx = p * 256 + tid;
      const int r = idx >> 4, c4 = (idx & 15) * 4;
      float4 f = *reinterpret_cast<const float4*>(&enc[(size_t)(b * S + s0 + r) * H + h0 + c4]);
      tile[r][c4 + 0] = f.x; tile[r][c4 + 1] = f.y; tile[r][c4 + 2] = f.z; tile[r][c4 + 3] = f.w;
    }
    __syncthreads();
#pragma unroll
    for (int p = 0; p < 2; ++p) {
      const int chunk = p * 256 + tid;
      const int rr = chunk >> 3, cc0 = (chunk & 7) * 8;
      short8 o;
#pragma unroll
      for (int j = 0; j < 8; ++j) o[j] = f2bf(tile[cc0 + j][rr]);
      *reinterpret_cast<short8*>(&e_t[(size_t)(b * H + h0 + rr) * S + s0 + cc0]) = o;
    }
  } else {
    int vi = (blockIdx.x - 256) * 256 + tid;  // vec4 index; Ws 65536 | Wh 65536 | Wo 131072
    if (vi >= 262144) return;
    const float* src; short* dst; int local; float scale;
    if (vi < 65536)       { src = ws; dst = base + OFF_WSB; local = vi;          scale = C2; }
    else if (vi < 131072) { src = wh; dst = base + OFF_WHB; local = vi - 65536;  scale = C2; }
    else                  { src = wo; dst = base + OFF_WOB; local = vi - 131072; scale = 1.f; }
    float4 f = reinterpret_cast<const float4*>(src)[local];
    short4v o;
    o.x = f2bf(f.x * scale); o.y = f2bf(f.y * scale);
    o.z = f2bf(f.z * scale); o.w = f2bf(f.w * scale);
    *reinterpret_cast<short4v*>(dst + (size_t)local * 4) = o;
  }
}

// ---- MFMA GEMM core: 64x64 tile, 256 thr (4 waves 2x2), BK=64, XOR-swizzled LDS.
//      C[m][n] = sum_k A[m][k] * Wt[n][k]. A is bf16 or f32 (converted at staging). ----
template <bool AF32>
DEVINL void gemm_tile(const void* __restrict__ Av, int lda,
                      const short* __restrict__ Wt, int ldw, int K,
                      int bm, int bn, short* As, short* Bs, f32x4 acc[2][2]) {
  const int tid = threadIdx.x;
  const int lane = tid & 63;
  const int wm = (tid >> 6) >> 1, wn = (tid >> 6) & 1;
  const int g = lane >> 4, r = lane & 15;
  for (int k0 = 0; k0 < K; k0 += 64) {
    __syncthreads();
#pragma unroll
    for (int p = 0; p < 2; ++p) {
      const int idx = p * 256 + tid;
      const int row = idx >> 3, c = idx & 7;
      short8 av;
      if (AF32) {
        const float* Af = (const float*)Av;
        float4 f1 = *reinterpret_cast<const float4*>(&Af[(size_t)(bm + row) * lda + k0 + c * 8]);
        float4 f2 = *reinterpret_cast<const float4*>(&Af[(size_t)(bm + row) * lda + k0 + c * 8 + 4]);
        av[0] = f2bf(f1.x); av[1] = f2bf(f1.y); av[2] = f2bf(f1.z); av[3] = f2bf(f1.w);
        av[4] = f2bf(f2.x); av[5] = f2bf(f2.y); av[6] = f2bf(f2.z); av[7] = f2bf(f2.w);
      } else {
        const short* Ab = (const short*)Av;
        av = *reinterpret_cast<const short8*>(&Ab[(size_t)(bm + row) * lda + k0 + c * 8]);
      }
      short8 wv = *reinterpret_cast<const short8*>(&Wt[(size_t)(bn + row) * ldw + k0 + c * 8]);
      *reinterpret_cast<short8*>(&As[row * 64 + ((c ^ (row & 7)) * 8)]) = av;
      *reinterpret_cast<short8*>(&Bs[row * 64 + ((c ^ (row & 7)) * 8)]) = wv;
    }
    __syncthreads();
#pragma unroll
    for (int kc = 0; kc < 2; ++kc) {
      short8 af[2], bfr[2];
#pragma unroll
      for (int mb = 0; mb < 2; ++mb) {
        const int ra = wm * 32 + mb * 16 + r;
        af[mb] = *reinterpret_cast<const short8*>(&As[ra * 64 + (((kc * 4 + g) ^ (r & 7)) * 8)]);
      }
#pragma unroll
      for (int nb = 0; nb < 2; ++nb) {
        const int rb = wn * 32 + nb * 16 + r;
        bfr[nb] = *reinterpret_cast<const short8*>(&Bs[rb * 64 + (((kc * 4 + g) ^ (r & 7)) * 8)]);
      }
#pragma unroll
      for (int mb = 0; mb < 2; ++mb)
#pragma unroll
        for (int nb = 0; nb < 2; ++nb)
          acc[mb][nb] = __builtin_amdgcn_mfma_f32_16x16x32_bf16(af[mb], bfr[nb], acc[mb][nb], 0, 0, 0);
    }
  }
}

// blocks 0..127:   eq = exp2(query @ (C2*W_s)^T) -> f32 row-major [b*T+t][h]
// blocks 128..383: eh = exp2(enc @ (C2*W_h)^T)   -> bf16 TRANSPOSED [b][h][s]
__global__ __launch_bounds__(256) void gemm_proj_kernel(
    const float* __restrict__ query, const float* __restrict__ enc,
    const short* __restrict__ Wsb, const short* __restrict__ Whb,
    float* __restrict__ eq, short* __restrict__ eh_t) {
  __shared__ short As[64 * 64], Bs[64 * 64];
  f32x4 acc[2][2];
#pragma unroll
  for (int i = 0; i < 2; ++i)
#pragma unroll
    for (int j = 0; j < 2; ++j) acc[i][j] = (f32x4){0.f, 0.f, 0.f, 0.f};
  int bid = blockIdx.x;
  const bool is_q = bid < 128;
  const float* A; const short* Wt;
  if (is_q) { A = query; Wt = Wsb; }
  else      { bid -= 128; A = enc; Wt = Whb; }
  const int bm = (bid >> 3) * 64, bn = (bid & 7) * 64;
  gemm_tile<true>(A, H, Wt, H, H, bm, bn, As, Bs, acc);
  const int lane = threadIdx.x & 63, wave = threadIdx.x >> 6;
  const int wm = wave >> 1, wn = wave & 1, g = lane >> 4, r = lane & 15;
#pragma unroll
  for (int mb = 0; mb < 2; ++mb)
#pragma unroll
    for (int nb = 0; nb < 2; ++nb) {
      const int m0 = bm + wm * 32 + mb * 16 + g * 4;  // base of 4 consecutive rows
      const int col = bn + wn * 32 + nb * 16 + r;
      if (is_q) {
#pragma unroll
        for (int i = 0; i < 4; ++i)
          eq[(size_t)(m0 + i) * H + col] = __builtin_amdgcn_exp2f(acc[mb][nb][i]);
      } else {
        // rows are s-consecutive within one b (S=256 divides tiles)
        const int bb = m0 >> 8, sl = m0 & 255;
        short4v o;
        o.x = f2bf(__builtin_amdgcn_exp2f(acc[mb][nb][0]));
        o.y = f2bf(__builtin_amdgcn_exp2f(acc[mb][nb][1]));
        o.z = f2bf(__builtin_amdgcn_exp2f(acc[mb][nb][2]));
        o.w = f2bf(__builtin_amdgcn_exp2f(acc[mb][nb][3]));
        *reinterpret_cast<short4v*>(&eh_t[((size_t)bb * H + col) * S + sl]) = o;
      }
    }
}

// ---- scores + softmax -> attn bf16.
// Block = one t-row: 512 thr = 8 waves = 4 s-groups x 2 H-halves. Lane owns s=sg*64+lane.
// tanh identity: tanh(q+h) = 1 - 2/(1 + exp2(C2*q)*exp2(C2*h)) = 1 - 2*rcp(fma(eq,eh,1)).
// Sum_h v_h (const across s) dropped via softmax shift-invariance.
// Per element: lshl(bf16->f32) + fma + rcp + fma = 3 VALU + 1 trans. NO exp2 in loop.
__global__ __launch_bounds__(512) void attn_kernel(
    const float* __restrict__ eq, const short* __restrict__ eh_t,
    const float* __restrict__ v, const int* __restrict__ lens,
    short* __restrict__ attn_bf) {
  __shared__ float s_part[2][S];
  __shared__ float red_m[4], red_s[4];
  const int tid = threadIdx.x, lane = tid & 63, wave = tid >> 6;
  const int sg = wave & 3, half = wave >> 2;
  const int b = blockIdx.x >> 7;           // T = 128 blocks per batch
  const int t = blockIdx.x & 127;
  const int s = sg * 64 + lane;

  const float* qp = eq + (size_t)(b * T + t) * H + half * (H / 2);
  const float* vp = v + half * (H / 2);
  const short* ep = eh_t + (size_t)b * H * S + (size_t)(half * (H / 2)) * S + s;

  float a0 = 0.f, a1 = 0.f;
  for (int ch = 0; ch < H / 16; ++ch) {    // 32 chunks of 8 over this half
    const int h = ch * 8;
    const f32x4 qa = *reinterpret_cast<const f32x4*>(qp + h);
    const f32x4 qb = *reinterpret_cast<const f32x4*>(qp + h + 4);
    const f32x4 va = *reinterpret_cast<const f32x4*>(vp + h);
    const f32x4 vb = *reinterpret_cast<const f32x4*>(vp + h + 4);
    const short* hh = ep + (size_t)h * S;
#pragma unroll
    for (int j = 0; j < 4; ++j) {
      float e0 = bf2f(hh[(size_t)j * S]);
      float e1 = bf2f(hh[(size_t)(j + 4) * S]);
      a0 = fmaf(va[j], __builtin_amdgcn_rcpf(fmaf(qa[j], e0, 1.0f)), a0);
      a1 = fmaf(vb[j], __builtin_amdgcn_rcpf(fmaf(qb[j], e1, 1.0f)), a1);
    }
  }
  s_part[half][s] = a0 + a1;
  __syncthreads();

  // all 8 waves redundantly finalize (uniform control flow; identical values)
  const float acc = s_part[0][s] + s_part[1][s];
  const int len = lens[b];
  const float y = (s < len) ? (-2.0f * L2E * acc) : -1e30f;  // log2-domain score

  float m = y;
#pragma unroll
  for (int off = 32; off > 0; off >>= 1) m = fmaxf(m, __shfl_xor(m, off));
  if (lane == 0) red_m[sg] = m;   // both halves write identical value
  __syncthreads();
  const float mt = fmaxf(fmaxf(red_m[0], red_m[1]), fmaxf(red_m[2], red_m[3]));
  const float p = __builtin_amdgcn_exp2f(y - mt);
  float sum = p;
#pragma unroll
  for (int off = 32; off > 0; off >>= 1) sum += __shfl_xor(sum, off);
  if (lane == 0) red_s[sg] = sum;
  __syncthreads();
  if (half == 0) {
    const float tot = red_s[0] + red_s[1] + red_s[2] + red_s[3];
    attn_bf[(size_t)(b * T + t) * S + s] = f2bf(p * __builtin_amdgcn_rcpf(tot));
  }
}

// ctx = attn @ enc  (via e_t as Wt). A rows: [B*T][S]; Wt rows: e_t[b][h][s].
__global__ __launch_bounds__(256) void ctx_gemm_kernel(
    const short* __restrict__ attn_bf, const short* __restrict__ e_t,
    short* __restrict__ ctx_bf) {
  __shared__ short As[64 * 64], Bs[64 * 64];
  f32x4 acc[2][2];
#pragma unroll
  for (int i = 0; i < 2; ++i)
#pragma unroll
    for (int j = 0; j < 2; ++j) acc[i][j] = (f32x4){0.f, 0.f, 0.f, 0.f};
  const int bm = blockIdx.x * 64;          // over B*T = 1024 rows
  const int bn = blockIdx.y * 64;          // over H
  const int batch = bm >> 7;               // T = 128 rows per batch
  gemm_tile<false>(attn_bf, S, e_t + (size_t)batch * H * S, S, S, bm, bn, As, Bs, acc);
  const int lane = threadIdx.x & 63, wave = threadIdx.x >> 6;
  const int wm = wave >> 1, wn = wave & 1, g = lane >> 4, r = lane & 15;
#pragma unroll
  for (int mb = 0; mb < 2; ++mb)
#pragma unroll
    for (int nb = 0; nb < 2; ++nb)
#pragma unroll
      for (int i = 0; i < 4; ++i) {
        const int row = bm + wm * 32 + mb * 16 + g * 4 + i;
        const int col = bn + wn * 32 + nb * 16 + r;
        ctx_bf[(size_t)row * H + col] = f2bf(acc[mb][nb][i]);
      }
}

// out = tanh([ctx | query] @ W_out^T + b_out), f32 out.
__global__ __launch_bounds__(256) void gemm_out_kernel(
    const short* __restrict__ ctx_bf, const float* __restrict__ query,
    const short* __restrict__ Wob, const float* __restrict__ bias,
    float* __restrict__ out) {
  __shared__ short As[64 * 64], Bs[64 * 64];
  f32x4 acc[2][2];
#pragma unroll
  for (int i = 0; i < 2; ++i)
#pragma unroll
    for (int j = 0; j < 2; ++j) acc[i][j] = (f32x4){0.f, 0.f, 0.f, 0.f};
  const int bm = (blockIdx.x >> 3) * 64, bn = (blockIdx.x & 7) * 64;
  gemm_tile<false>(ctx_bf, H, Wob, 2 * H, H, bm, bn, As, Bs, acc);
  gemm_tile<true>(query, H, Wob + H, 2 * H, H, bm, bn, As, Bs, acc);
  const int lane = threadIdx.x & 63, wave = threadIdx.x >> 6;
  const int wm = wave >> 1, wn = wave & 1, g = lane >> 4, r = lane & 15;
#pragma unroll
  for (int mb = 0; mb < 2; ++mb)
#pragma unroll
    for (int nb = 0; nb < 2; ++nb) {
      const int col = bn + wn * 32 + nb * 16 + r;
      const float bb = bias[col];
#pragma unroll
      for (int i = 0; i < 4; ++i) {
        const int row = bm + wm * 32 + mb * 16 + g * 4 + i;
        out[(size_t)row * H + col] = fast_tanh(acc[mb][nb][i] + bb);
      }
    }
}

extern "C" void kernel_launch(void* const* d_in, const int* in_sizes, int n_in,
                              void* d_out, int out_size, void* d_ws, size_t ws_size,
                              hipStream_t stream) {
  const float* query = (const float*)d_in[0];  // (B,T,H)
  const float* enc = (const float*)d_in[1];    // (B,S,H)
  const int* lens = (const int*)d_in[2];       // (B)
  const float* W_s = (const float*)d_in[3];    // (H,H)
  const float* W_h = (const float*)d_in[4];    // (H,H)
  const float* v = (const float*)d_in[5];      // (H)
  const float* W_out = (const float*)d_in[6];  // (H,2H)
  const float* b_out = (const float*)d_in[7];  // (H)
  float* out = (float*)d_out;                  // (B,T,H)

  short* wsb = (short*)d_ws;
  short* Wsb = wsb + OFF_WSB;
  short* Whb = wsb + OFF_WHB;
  short* Wob = wsb + OFF_WOB;
  short* eh_t = wsb + OFF_EH;
  short* e_t = wsb + OFF_ET;
  short* attn_bf = wsb + OFF_ATT;
  short* ctx_bf = wsb + OFF_CTX;
  float* eq = (float*)(wsb + OFF_EQ);

  prep_kernel<<<1280, 256, 0, stream>>>(W_s, W_h, W_out, enc, wsb);
  gemm_proj_kernel<<<384, 256, 0, stream>>>(query, enc, Wsb, Whb, eq, eh_t);
  attn_kernel<<<B * T, 512, 0, stream>>>(eq, eh_t, v, lens, attn_bf);
  ctx_gemm_kernel<<<dim3(16, 8), 256, 0, stream>>>(attn_bf, e_t, ctx_bf);
  gemm_out_kernel<<<128, 256, 0, stream>>>(ctx_bf, query, Wob, b_out, out);
}